// Round 7
// baseline (211.914 us; speedup 1.0000x reference)
//
#include <hip/hip_runtime.h>
#include <hip/hip_bf16.h>

constexpr int EMBED = 1024;
constexpr int NHEAD = 16;
constexpr int HDIM  = 64;
constexpr int BATCH = 2;
constexpr int SEQ   = 2048;
constexpr int MROWS = BATCH * SEQ;   // 4096
constexpr int NKB   = EMBED / 32;    // 32 k-blocks of 32
constexpr int NT    = SEQ / 64;      // 32 KV tiles

typedef __attribute__((ext_vector_type(8)))  short          bf8;
typedef __attribute__((ext_vector_type(8)))  unsigned short us8;
typedef __attribute__((ext_vector_type(16))) float          f32x16;
typedef __attribute__((ext_vector_type(2)))  int            i32x2;

__device__ __forceinline__ unsigned short f2bf(float f) {  // RNE fp32->bf16
  unsigned u = __float_as_uint(f);
  u += 0x7fffu + ((u >> 16) & 1u);
  return (unsigned short)(u >> 16);
}
__device__ __forceinline__ float bf2f(unsigned short h) {
  return __uint_as_float((unsigned)h << 16);
}
__device__ __forceinline__ void async16(const void* g, void* l) {
  __builtin_amdgcn_global_load_lds(
      (const __attribute__((address_space(1))) unsigned int*)g,
      (__attribute__((address_space(3))) unsigned int*)l, 16, 0, 0);
}
// lane-half exchange: returns {d, s}: d = own(lane<32)/partner(lane>=32) of a|b,
// s = partner(lane<32)/own(lane>=32).  (v_permlane32_swap_b32 semantics.)
__device__ __forceinline__ i32x2 swap32(int a, int b) {
  return __builtin_amdgcn_permlane32_swap(a, b, false, false);
}

// ---------------------------------------------------------------------------
// bf16 pack of x: unit u = row-pair, 128B per (u,t): 8 slots of 16B.
// slot s holds c = s^(u&7): par=c>>2 (row 2u+par), kq=c&3 (k=t*32+kq*8).
// ---------------------------------------------------------------------------
__global__ __launch_bounds__(256) void pack_x_bf16_k(
    const float* __restrict__ in, char* __restrict__ outp)
{
  int sid = blockIdx.x * 256 + threadIdx.x;   // 0..524287
  int s = sid & 7, t = (sid >> 3) & 31, u = sid >> 8;
  int c = s ^ (u & 7);
  int par = c >> 2, kq = c & 3;
  const float* src = in + (size_t)(2 * u + par) * EMBED + t * 32 + kq * 8;
  us8 o;
  #pragma unroll
  for (int e = 0; e < 8; ++e) o[e] = f2bf(src[e]);
  *(us8*)(outp + ((size_t)sid << 4)) = o;
}

// bf16 pack of W^T (keyed by column-pair), 3 matrices (y selects), 2MB each.
__global__ __launch_bounds__(256) void pack_w_bf16_k(
    const float* __restrict__ W0, const float* __restrict__ W1,
    const float* __restrict__ W2, char* __restrict__ outp)
{
  const int y = blockIdx.y;
  const float* W = (y == 0) ? W0 : (y == 1) ? W1 : W2;
  char* op = outp + ((size_t)y << 21);
  int sid = blockIdx.x * 256 + threadIdx.x;   // 0..131071
  int s = sid & 7, t = (sid >> 3) & 31, u = sid >> 8;   // u: col-pair 0..511
  int c = s ^ (u & 7);
  int par = c >> 2, kq = c & 3;
  const float* src = W + (size_t)(t * 32 + kq * 8) * EMBED + (2 * u + par);
  us8 o;
  #pragma unroll
  for (int e = 0; e < 8; ++e) o[e] = f2bf(src[(size_t)e * EMBED]);
  *(us8*)(op + ((size_t)sid << 4)) = o;
}

// split-bf16 pack of Wo^T (256B units, 16 slots: par/plane/kb8), 4MB.
__global__ __launch_bounds__(256) void pack_wo_split_k(
    const float* __restrict__ W, char* __restrict__ outp)
{
  int sid = blockIdx.x * 256 + threadIdx.x;   // 0..262143
  int s = sid & 15, t = (sid >> 4) & 31, u = sid >> 9;   // u: col-pair 0..511
  int c = s ^ (u & 15);
  int par = c >> 3, pl = (c >> 2) & 1, kb8 = c & 3;
  const float* src = W + (size_t)(t * 32 + kb8 * 8) * EMBED + (2 * u + par);
  us8 o;
  #pragma unroll
  for (int e = 0; e < 8; ++e) {
    float f = src[(size_t)e * EMBED];
    unsigned short h = f2bf(f);
    o[e] = pl ? f2bf(f - bf2f(h)) : h;
  }
  *(us8*)(outp + ((size_t)sid << 4)) = o;
}

// ---------------------------------------------------------------------------
// QKV GEMM, plain bf16, dbuf 2-phase. 128x256 tile, BK=32, 4 waves (1x4),
// per-wave 4x2 frags of 32x32x16 -> 16 MFMA + 12 ds_read_b128 per K-step.
// z==0 output pre-scaled by log2e/64 (log2-domain attention scores).
// ---------------------------------------------------------------------------
__global__ __launch_bounds__(256) void gemm_qkv_bf16_k(
    const char* __restrict__ Apk, const char* __restrict__ Wpk,
    const float* __restrict__ B0, const float* __restrict__ B1, const float* __restrict__ B2,
    unsigned short* __restrict__ Cb0, unsigned short* __restrict__ Cb1,
    unsigned short* __restrict__ Cb2)
{
  __shared__ __align__(16) char Asm[16384];   // 2 x 8KB
  __shared__ __align__(16) char Wsm[32768];   // 2 x 16KB

  const int tid  = threadIdx.x;
  const int lane = tid & 63;
  const int wid  = tid >> 6;                  // wave col 0..3
  const int ln31 = lane & 31, lhalf = lane >> 5;

  const int bid = blockIdx.x;                 // 384 blocks
  const int swz = (bid & 7) * 48 + (bid >> 3);
  const int rp  = swz / 12;                   // 0..31 row panel
  const int sub = swz - rp * 12;
  const int z   = sub >> 2, cb = sub & 3;

  const char*  Wz = Wpk + ((size_t)z << 21);
  const float* Bv = (z == 0) ? B0 : (z == 1) ? B1 : B2;

  const int M0 = rp * 128, N0 = cb * 256;
  const int U0 = rp * 64,  V0 = cb * 128;

  const char* ab[2]; int aoff[2];
  const char* wb[4]; int woff[4];
  #pragma unroll
  for (int i = 0; i < 2; ++i) {
    int idx = i * 256 + tid;
    int ul = idx >> 3, sl = idx & 7;
    ab[i] = Apk + ((size_t)(U0 + ul) << 12) + (sl << 4);
    aoff[i] = i * 4096 + (tid >> 6) * 1024;
  }
  #pragma unroll
  for (int i = 0; i < 4; ++i) {
    int idx = i * 256 + tid;
    int ul = idx >> 3, sl = idx & 7;
    wb[i] = Wz + ((size_t)(V0 + ul) << 12) + (sl << 4);
    woff[i] = i * 4096 + (tid >> 6) * 1024;
  }

  f32x16 acc[4][2];
  #pragma unroll
  for (int mi = 0; mi < 4; ++mi)
    #pragma unroll
    for (int ni = 0; ni < 2; ++ni)
      #pragma unroll
      for (int q = 0; q < 16; ++q) acc[mi][ni][q] = 0.f;

  #pragma unroll
  for (int i = 0; i < 2; ++i) async16(ab[i], &Asm[aoff[i]]);
  #pragma unroll
  for (int i = 0; i < 4; ++i) async16(wb[i], &Wsm[woff[i]]);
  __syncthreads();

  for (int t = 0; t < NKB; ++t) {
    const int c = t & 1;
    if (t + 1 < NKB) {
      #pragma unroll
      for (int i = 0; i < 2; ++i)
        async16(ab[i] + ((t + 1) << 7), &Asm[(c ^ 1) * 8192 + aoff[i]]);
      #pragma unroll
      for (int i = 0; i < 4; ++i)
        async16(wb[i] + ((t + 1) << 7), &Wsm[(c ^ 1) * 16384 + woff[i]]);
    }
    const char* Ab = Asm + c * 8192;
    const char* Wb = Wsm + c * 16384;
    #pragma unroll
    for (int kb = 0; kb < 2; ++kb) {
      const int kq = (kb << 1) | lhalf;
      bf8 a[4], b[2];
      #pragma unroll
      for (int mi = 0; mi < 4; ++mi) {
        int m = mi * 32 + ln31;
        int u = m >> 1;
        int s = (((m & 1) << 2) | kq) ^ (u & 7);
        a[mi] = *(const bf8*)(Ab + u * 128 + s * 16);
      }
      #pragma unroll
      for (int ni = 0; ni < 2; ++ni) {
        int n = wid * 64 + ni * 32 + ln31;
        int u = n >> 1;
        int s = (((n & 1) << 2) | kq) ^ (u & 7);
        b[ni] = *(const bf8*)(Wb + u * 128 + s * 16);
      }
      #pragma unroll
      for (int mi = 0; mi < 4; ++mi)
        #pragma unroll
        for (int ni = 0; ni < 2; ++ni)
          acc[mi][ni] = __builtin_amdgcn_mfma_f32_32x32x16_bf16(a[mi], b[ni], acc[mi][ni], 0, 0, 0);
    }
    __syncthreads();
  }

  unsigned short* Cb = (z == 0) ? Cb0 : (z == 1) ? Cb1 : Cb2;
  const float sc = (z == 0) ? (1.44269504088896f / 64.0f) : 1.0f;
  #pragma unroll
  for (int ni = 0; ni < 2; ++ni) {
    int col = N0 + wid * 64 + ni * 32 + ln31;
    float bb = Bv[col];
    #pragma unroll
    for (int mi = 0; mi < 4; ++mi)
      #pragma unroll
      for (int r = 0; r < 16; ++r) {
        int row = M0 + mi * 32 + (r & 3) + ((r >> 2) << 3) + (lhalf << 2);
        Cb[(size_t)row * EMBED + col] = f2bf((acc[mi][ni][r] + bb) * sc);
      }
  }
}

// ---------------------------------------------------------------------------
// Output projection: split-bf16 3-term MFMA GEMM, dbuf 2-phase (unchanged).
// ---------------------------------------------------------------------------
__global__ __launch_bounds__(256) void gemm_out_split_k(
    const char* __restrict__ Apack, const char* __restrict__ Wpack,
    const float* __restrict__ Bv, float* __restrict__ Cf)
{
  __shared__ __align__(16) char Asm[32768];   // 2 x 16KB
  __shared__ __align__(16) char Wsm[32768];

  const int tid  = threadIdx.x;
  const int lane = tid & 63;
  const int wid  = tid >> 6;
  const int wr   = wid >> 1, wc = wid & 1;
  const int ln31 = lane & 31, lhalf = lane >> 5;

  const int bid = blockIdx.x;                 // 256 blocks
  const int swz = (bid & 7) * 32 + (bid >> 3);
  const int rp  = swz >> 3, cb = swz & 7;

  const int M0 = rp * 128, N0 = cb * 128;
  const int U0 = M0 >> 1, V0 = N0 >> 1;

  const char* ab[4]; const char* wb[4]; int ldoff[4];
  #pragma unroll
  for (int i = 0; i < 4; ++i) {
    int ul = i * 16 + (tid >> 4);
    int so = (tid & 15) << 4;
    ab[i] = Apack + ((size_t)(U0 + ul) << 13) + so;
    wb[i] = Wpack + ((size_t)(V0 + ul) << 13) + so;
    ldoff[i] = i * 4096 + (tid >> 6) * 1024;
  }

  f32x16 acc[2][2];
  #pragma unroll
  for (int mi = 0; mi < 2; ++mi)
    #pragma unroll
    for (int ni = 0; ni < 2; ++ni)
      #pragma unroll
      for (int q = 0; q < 16; ++q) acc[mi][ni][q] = 0.f;

  #pragma unroll
  for (int i = 0; i < 4; ++i) {
    async16(ab[i], &Asm[ldoff[i]]);
    async16(wb[i], &Wsm[ldoff[i]]);
  }
  __syncthreads();

  for (int t = 0; t < NKB; ++t) {
    const int c = t & 1;
    if (t + 1 < NKB) {
      #pragma unroll
      for (int i = 0; i < 4; ++i) {
        async16(ab[i] + ((t + 1) << 8), &Asm[(c ^ 1) * 16384 + ldoff[i]]);
        async16(wb[i] + ((t + 1) << 8), &Wsm[(c ^ 1) * 16384 + ldoff[i]]);
      }
    }
    const char* Ab = Asm + c * 16384;
    const char* Wb = Wsm + c * 16384;
    #pragma unroll
    for (int h = 0; h < 2; ++h) {
      const int kb = h * 2 + lhalf;
      bf8 aH[2], aL[2], bH[2], bL[2];
      #pragma unroll
      for (int mi = 0; mi < 2; ++mi) {
        int m = wr * 64 + mi * 32 + ln31;
        int u = m >> 1;
        int sH = (((m & 1) << 3) | kb) ^ (u & 15);
        aH[mi] = *(const bf8*)(Ab + u * 256 + sH * 16);
        aL[mi] = *(const bf8*)(Ab + u * 256 + (sH ^ 4) * 16);
      }
      #pragma unroll
      for (int ni = 0; ni < 2; ++ni) {
        int n = wc * 64 + ni * 32 + ln31;
        int u = n >> 1;
        int sH = (((n & 1) << 3) | kb) ^ (u & 15);
        bH[ni] = *(const bf8*)(Wb + u * 256 + sH * 16);
        bL[ni] = *(const bf8*)(Wb + u * 256 + (sH ^ 4) * 16);
      }
      #pragma unroll
      for (int mi = 0; mi < 2; ++mi)
        #pragma unroll
        for (int ni = 0; ni < 2; ++ni) {
          acc[mi][ni] = __builtin_amdgcn_mfma_f32_32x32x16_bf16(aH[mi], bH[ni], acc[mi][ni], 0, 0, 0);
          acc[mi][ni] = __builtin_amdgcn_mfma_f32_32x32x16_bf16(aH[mi], bL[ni], acc[mi][ni], 0, 0, 0);
          acc[mi][ni] = __builtin_amdgcn_mfma_f32_32x32x16_bf16(aL[mi], bH[ni], acc[mi][ni], 0, 0, 0);
        }
    }
    __syncthreads();
  }

  #pragma unroll
  for (int ni = 0; ni < 2; ++ni) {
    int col = N0 + wc * 64 + ni * 32 + ln31;
    float bb = Bv[col];
    #pragma unroll
    for (int mi = 0; mi < 2; ++mi)
      #pragma unroll
      for (int r = 0; r < 16; ++r) {
        int row = M0 + wr * 64 + mi * 32 + (r & 3) + ((r >> 2) << 3) + (lhalf << 2);
        Cf[(size_t)row * EMBED + col] = acc[mi][ni][r] + bb;
      }
  }
}

// ---------------------------------------------------------------------------
// MFMA flash attention, log2-domain softmax, defer-max, cvt_pk + permlane.
// ---------------------------------------------------------------------------
__global__ __launch_bounds__(256) void attn_mfma_k(
    const unsigned short* __restrict__ Qb, const unsigned short* __restrict__ Kb,
    const unsigned short* __restrict__ Vb, char* __restrict__ A2)
{
  __shared__ __align__(16) char lds[32768];   // buf c: K @ c*16K, V^T @ c*16K+8K

  const int bid = blockIdx.x;
  const int swz = (bid & 7) * 64 + (bid >> 3);
  const int qt = swz & 15, h = (swz >> 4) & 15, b = swz >> 8;

  const int tid  = threadIdx.x;
  const int lane = tid & 63;
  const int w    = tid >> 6;
  const int ln31 = lane & 31, lh = lane >> 5;
  const int l7   = ln31 & 7;

  const int q0 = qt * 128;

  // Q fragments direct from global (pre-scaled by log2e/64 in GEMM epilogue)
  bf8 qf[4];
  {
    const size_t qoff = (size_t)(b * SEQ + q0 + w * 32 + ln31) * EMBED + h * HDIM;
    #pragma unroll
    for (int kd = 0; kd < 4; ++kd)
      qf[kd] = *(const bf8*)(Qb + qoff + (2 * kd + lh) * 8);
  }

  const unsigned short* ksrc[2]; int kldoff[2];
  #pragma unroll
  for (int i = 0; i < 2; ++i) {
    int idx = i * 256 + tid;
    int r = idx >> 3, s7 = idx & 7;
    int un = s7 ^ (r & 7);
    ksrc[i] = Kb + (size_t)(b * SEQ + r) * EMBED + h * HDIM + un * 8;
    kldoff[i] = i * 4096 + (tid >> 6) * 1024;
  }
  const int kp = tid & 31, d8 = (tid >> 5) << 3;
  const unsigned short* vsrc = Vb + (size_t)(b * SEQ + 2 * kp) * EMBED + h * HDIM + d8;

  us8 v0, v1;
  #pragma unroll
  for (int i = 0; i < 2; ++i) async16(ksrc[i], lds + kldoff[i]);
  v0 = *(const us8*)(vsrc);
  v1 = *(const us8*)(vsrc + EMBED);
  {
    union { us8 v; unsigned u[4]; } U0, U1; U0.v = v0; U1.v = v1;
    #pragma unroll
    for (int q2 = 0; q2 < 4; ++q2) {
      unsigned lo = __builtin_amdgcn_perm(U1.u[q2], U0.u[q2], 0x05040100u);
      unsigned hi = __builtin_amdgcn_perm(U1.u[q2], U0.u[q2], 0x07060302u);
      int d0 = d8 + 2 * q2, d1 = d0 + 1;
      *(unsigned*)(lds + 8192 + d0 * 128 + (((kp >> 2) ^ (d0 & 7)) << 4) + ((kp & 3) << 2)) = lo;
      *(unsigned*)(lds + 8192 + d1 * 128 + (((kp >> 2) ^ (d1 & 7)) << 4) + ((kp & 3) << 2)) = hi;
    }
  }
  __syncthreads();

  f32x16 oacc[2];
  #pragma unroll
  for (int df = 0; df < 2; ++df)
    #pragma unroll
    for (int r = 0; r < 16; ++r) oacc[df][r] = 0.f;
  float m_run = -1e30f, l_run = 0.f;

  for (int t = 0; t < NT; ++t) {
    const int c = t & 1;
    const int tn = (t + 1 < NT) ? t + 1 : t;
    #pragma unroll
    for (int i = 0; i < 2; ++i)
      async16(ksrc[i] + (size_t)(tn * 64) * EMBED, lds + (c ^ 1) * 16384 + kldoff[i]);
    v0 = *(const us8*)(vsrc + (size_t)(tn * 64) * EMBED);
    v1 = *(const us8*)(vsrc + (size_t)(tn * 64) * EMBED + EMBED);

    // S^T = K * Q^T (log2 domain) from buf c
    f32x16 sacc[2];
    #pragma unroll
    for (int kf = 0; kf < 2; ++kf)
      #pragma unroll
      for (int r = 0; r < 16; ++r) sacc[kf][r] = 0.f;
    __builtin_amdgcn_s_setprio(1);
    #pragma unroll
    for (int kf = 0; kf < 2; ++kf)
      #pragma unroll
      for (int kd = 0; kd < 4; ++kd) {
        bf8 ka = *(const bf8*)(lds + c * 16384 + (32 * kf + ln31) * 128 + (((2 * kd + lh) ^ l7) << 4));
        sacc[kf] = __builtin_amdgcn_mfma_f32_32x32x16_bf16(ka, qf[kd], sacc[kf], 0, 0, 0);
      }
    __builtin_amdgcn_s_setprio(0);

    // online softmax, log2 domain, defer-max (T13, THR=8 -> P <= 256)
    float mx = sacc[0][0];
    #pragma unroll
    for (int kf = 0; kf < 2; ++kf)
      #pragma unroll
      for (int r = 0; r < 16; ++r) mx = fmaxf(mx, sacc[kf][r]);
    {
      i32x2 ms = swap32(__float_as_int(mx), __float_as_int(mx));
      mx = fmaxf(__int_as_float(ms[0]), __int_as_float(ms[1]));
    }
    if (__any(mx - m_run > 8.f)) {
      float mnew = fmaxf(m_run, mx);
      float corr = __builtin_amdgcn_exp2f(m_run - mnew);
      l_run *= corr;
      #pragma unroll
      for (int df = 0; df < 2; ++df)
        #pragma unroll
        for (int r = 0; r < 16; ++r) oacc[df][r] *= corr;
      m_run = mnew;
    }
    float psum = 0.f;
    #pragma unroll
    for (int kf = 0; kf < 2; ++kf)
      #pragma unroll
      for (int r = 0; r < 16; ++r) {
        float p = __builtin_amdgcn_exp2f(sacc[kf][r] - m_run);
        sacc[kf][r] = p; psum += p;
      }
    {
      i32x2 ps = swap32(__float_as_int(psum), __float_as_int(psum));
      psum = __int_as_float(ps[0]) + __int_as_float(ps[1]);
    }
    l_run += psum;

    // write next-tile V^T into buf^1
    {
      union { us8 v; unsigned u[4]; } U0, U1; U0.v = v0; U1.v = v1;
      #pragma unroll
      for (int q2 = 0; q2 < 4; ++q2) {
        unsigned lo = __builtin_amdgcn_perm(U1.u[q2], U0.u[q2], 0x05040100u);
        unsigned hi = __builtin_amdgcn_perm(U1.u[q2], U0.u[q2], 0x07060302u);
        int d0 = d8 + 2 * q2, d1 = d0 + 1;
        *(unsigned*)(lds + (c ^ 1) * 16384 + 8192 + d0 * 128 + (((kp >> 2) ^ (d0 & 7)) << 4) + ((kp & 3) << 2)) = lo;
        *(unsigned*)(lds + (c ^ 1) * 16384 + 8192 + d1 * 128 + (((kp >> 2) ^ (d1 & 7)) << 4) + ((kp & 3) << 2)) = hi;
      }
    }

    // pack P to bf16 pairs (packed cvt)
    unsigned pk[2][8];
    #pragma unroll
    for (int kf = 0; kf < 2; ++kf)
      #pragma unroll
      for (int g = 0; g < 4; ++g)
        #pragma unroll
        for (int j = 0; j < 2; ++j) {
          union { __hip_bfloat162 b; unsigned u; } cv;
          cv.b = __float22bfloat162_rn(
              float2{sacc[kf][4 * g + 2 * j], sacc[kf][4 * g + 2 * j + 1]});
          pk[kf][2 * g + j] = cv.u;
        }

    // O^T += V^T * P^T from buf c (permlane swap builds both frag halves)
    __builtin_amdgcn_s_setprio(1);
    #pragma unroll
    for (int kb = 0; kb < 4; ++kb) {
      const int kf = kb >> 1, b4 = (kb & 1) * 4;
      i32x2 r02 = swap32((int)pk[kf][b4 + 0], (int)pk[kf][b4 + 2]);
      i32x2 r13 = swap32((int)pk[kf][b4 + 1], (int)pk[kf][b4 + 3]);
      union { unsigned u[4]; bf8 v; } pf;
      pf.u[0] = (unsigned)r02[0]; pf.u[1] = (unsigned)r13[0];
      pf.u[2] = (unsigned)r02[1]; pf.u[3] = (unsigned)r13[1];
      #pragma unroll
      for (int df = 0; df < 2; ++df) {
        bf8 va = *(const bf8*)(lds + c * 16384 + 8192 + (32 * df + ln31) * 128 + (((2 * kb + lh) ^ l7) << 4));
        oacc[df] = __builtin_amdgcn_mfma_f32_32x32x16_bf16(va, pf.v, oacc[df], 0, 0, 0);
      }
    }
    __builtin_amdgcn_s_setprio(0);
    __syncthreads();
  }

  // epilogue: normalize, permlane exchange, write packed split-bf16
  const float inv = 1.0f / l_run;
  float fl[8][4], fh[8][4];
  #pragma unroll
  for (int df = 0; df < 2; ++df)
    #pragma unroll
    for (int r = 0; r < 16; ++r) {
      float o = oacc[df][r] * inv;
      i32x2 rr = swap32(__float_as_int(o), __float_as_int(o));
      fl[df * 4 + (r >> 2)][r & 3] = __int_as_float(rr[0]);
      fh[df * 4 + (r >> 2)][r & 3] = __int_as_float(rr[1]);
    }

  const int row = b * SEQ + q0 + w * 32 + ln31;
  const int u = row >> 1, par = row & 1;
  #pragma unroll
  for (int g = 0; g < 8; ++g) {
    us8 hi, lo;
    #pragma unroll
    for (int e = 0; e < 8; ++e) {
      float f = (e < 4) ? fl[g][e] : fh[g][e - 4];
      unsigned short h8 = f2bf(f);
      hi[e] = h8;
      lo[e] = f2bf(f - bf2f(h8));
    }
    int t_blk = 2 * h + (g >> 2), kb8 = g & 3;
    size_t ub = ((size_t)(u * NKB + t_blk)) << 8;
    int sH = ((par << 3) | kb8) ^ (u & 15);
    *(us8*)(A2 + ub + (sH << 4)) = hi;
    *(us8*)(A2 + ub + ((sH ^ 4) << 4)) = lo;
  }
}

// ---------------------------------------------------------------------------
extern "C" void kernel_launch(void* const* d_in, const int* in_sizes, int n_in,
                              void* d_out, int out_size, void* d_ws, size_t ws_size,
                              hipStream_t stream)
{
  const float* x  = (const float*)d_in[0];
  const float* Wq = (const float*)d_in[1];
  const float* bq = (const float*)d_in[2];
  const float* Wk = (const float*)d_in[3];
  const float* bk = (const float*)d_in[4];
  const float* Wv = (const float*)d_in[5];
  const float* bv = (const float*)d_in[6];
  const float* Wo = (const float*)d_in[7];
  const float* bo = (const float*)d_in[8];
  float* out = (float*)d_out;

  char* wsb = (char*)d_ws;
  char*           Xp  = wsb;                                         // 8MB
  char*           Wp3 = wsb + ((size_t)8  << 20);                    // 6MB
  char*           Wos = wsb + ((size_t)14 << 20);                    // 4MB
  unsigned short* Qbf = (unsigned short*)(wsb + ((size_t)18 << 20)); // 8MB
  unsigned short* Kbf = (unsigned short*)(wsb + ((size_t)26 << 20)); // 8MB
  unsigned short* Vbf = (unsigned short*)(wsb + ((size_t)34 << 20)); // 8MB
  char*           A2  = wsb + ((size_t)42 << 20);                    // 16MB

  pack_x_bf16_k<<<dim3(2048), dim3(256), 0, stream>>>(x, Xp);
  pack_w_bf16_k<<<dim3(512, 3), dim3(256), 0, stream>>>(Wq, Wk, Wv, Wp3);
  pack_wo_split_k<<<dim3(1024), dim3(256), 0, stream>>>(Wo, Wos);

  gemm_qkv_bf16_k<<<dim3(384), dim3(256), 0, stream>>>(
      Xp, Wp3, bq, bk, bv, Qbf, Kbf, Vbf);

  attn_mfma_k<<<dim3(512), dim3(256), 0, stream>>>(Qbf, Kbf, Vbf, A2);

  gemm_out_split_k<<<dim3(256), dim3(256), 0, stream>>>(A2, Wos, bo, out);
}

// Round 8
// 170.472 us; speedup vs baseline: 1.2431x; 1.2431x over previous
//
#include <hip/hip_runtime.h>
#include <hip/hip_bf16.h>

constexpr int EMBED = 1024;
constexpr int NHEAD = 16;
constexpr int HDIM  = 64;
constexpr int BATCH = 2;
constexpr int SEQ   = 2048;
constexpr int MROWS = BATCH * SEQ;   // 4096
constexpr int NKB   = EMBED / 32;    // 32 k-blocks of 32
constexpr int NT    = SEQ / 64;      // 32 KV tiles

typedef __attribute__((ext_vector_type(8)))  short          bf8;
typedef __attribute__((ext_vector_type(8)))  unsigned short us8;
typedef __attribute__((ext_vector_type(16))) float          f32x16;
typedef __attribute__((ext_vector_type(2)))  int            i32x2;

__device__ __forceinline__ unsigned short f2bf(float f) {  // RNE fp32->bf16
  unsigned u = __float_as_uint(f);
  u += 0x7fffu + ((u >> 16) & 1u);
  return (unsigned short)(u >> 16);
}
__device__ __forceinline__ float bf2f(unsigned short h) {
  return __uint_as_float((unsigned)h << 16);
}
__device__ __forceinline__ void async16(const void* g, void* l) {
  __builtin_amdgcn_global_load_lds(
      (const __attribute__((address_space(1))) unsigned int*)g,
      (__attribute__((address_space(3))) unsigned int*)l, 16, 0, 0);
}
__device__ __forceinline__ i32x2 swap32(int a, int b) {
  return __builtin_amdgcn_permlane32_swap(a, b, false, false);
}

// ---------------------------------------------------------------------------
// Fused pack kernel. Block ranges:
//   [0,2048)      : x -> bf16 128B-unit layout (8 slots/unit)
//   [2048,3584)   : Wq/Wk/Wv^T -> bf16 unit layout (512 blocks each)
//   [3584,4608)   : Wo^T -> split-bf16 256B-unit layout (16 slots/unit)
// ---------------------------------------------------------------------------
__global__ __launch_bounds__(256) void pack_all_k(
    const float* __restrict__ x,
    const float* __restrict__ Wq, const float* __restrict__ Wk,
    const float* __restrict__ Wv, const float* __restrict__ Wo,
    char* __restrict__ Xp, char* __restrict__ Wp3, char* __restrict__ Wos)
{
  const int blk = blockIdx.x;
  const int tid = threadIdx.x;
  if (blk < 2048) {
    int sid = blk * 256 + tid;                 // 0..524287
    int s = sid & 7, t = (sid >> 3) & 31, u = sid >> 8;
    int c = s ^ (u & 7);
    int par = c >> 2, kq = c & 3;
    const float* src = x + (size_t)(2 * u + par) * EMBED + t * 32 + kq * 8;
    us8 o;
    #pragma unroll
    for (int e = 0; e < 8; ++e) o[e] = f2bf(src[e]);
    *(us8*)(Xp + ((size_t)sid << 4)) = o;
  } else if (blk < 3584) {
    int bb = blk - 2048;
    int y = bb >> 9;                           // 0..2
    const float* W = (y == 0) ? Wq : (y == 1) ? Wk : Wv;
    char* op = Wp3 + ((size_t)y << 21);
    int sid = (bb & 511) * 256 + tid;          // 0..131071
    int s = sid & 7, t = (sid >> 3) & 31, u = sid >> 8;
    int c = s ^ (u & 7);
    int par = c >> 2, kq = c & 3;
    const float* src = W + (size_t)(t * 32 + kq * 8) * EMBED + (2 * u + par);
    us8 o;
    #pragma unroll
    for (int e = 0; e < 8; ++e) o[e] = f2bf(src[(size_t)e * EMBED]);
    *(us8*)(op + ((size_t)sid << 4)) = o;
  } else {
    int sid = (blk - 3584) * 256 + tid;        // 0..262143
    int s = sid & 15, t = (sid >> 4) & 31, u = sid >> 9;
    int c = s ^ (u & 15);
    int par = c >> 3, pl = (c >> 2) & 1, kb8 = c & 3;
    const float* src = Wo + (size_t)(t * 32 + kb8 * 8) * EMBED + (2 * u + par);
    us8 o;
    #pragma unroll
    for (int e = 0; e < 8; ++e) {
      float f = src[(size_t)e * EMBED];
      unsigned short h = f2bf(f);
      o[e] = pl ? f2bf(f - bf2f(h)) : h;
    }
    *(us8*)(Wos + ((size_t)sid << 4)) = o;
  }
}

// ---------------------------------------------------------------------------
// QKV GEMM, plain bf16, dbuf 2-phase (round-6 proven config).
// 128x128 tile, BK=32, 4 waves (2x2), 2x2 frags, 8 MFMA + 8 ds_read/K-step.
// z==0 output pre-scaled by log2e/64 (log2-domain attention scores).
// ---------------------------------------------------------------------------
__global__ __launch_bounds__(256) void gemm_qkv_bf16_k(
    const char* __restrict__ Apk, const char* __restrict__ Wpk,
    const float* __restrict__ B0, const float* __restrict__ B1, const float* __restrict__ B2,
    unsigned short* __restrict__ Cb0, unsigned short* __restrict__ Cb1,
    unsigned short* __restrict__ Cb2)
{
  __shared__ __align__(16) char Asm[16384];   // 2 x 8KB
  __shared__ __align__(16) char Wsm[16384];

  const int tid  = threadIdx.x;
  const int lane = tid & 63;
  const int wid  = tid >> 6;
  const int wr   = wid >> 1, wc = wid & 1;
  const int ln31 = lane & 31, lhalf = lane >> 5;

  const int bid = blockIdx.x;                 // 768 blocks
  const int swz = (bid & 7) * 96 + (bid >> 3);
  const int rp  = swz / 24;
  const int sub = swz - rp * 24;
  const int z   = sub >> 3, cb = sub & 7;

  const char*  Wz = Wpk + ((size_t)z << 21);
  const float* Bv = (z == 0) ? B0 : (z == 1) ? B1 : B2;

  const int M0 = rp * 128, N0 = cb * 128;
  const int U0 = M0 >> 1, V0 = N0 >> 1;

  const char* ab[2]; const char* wb[2]; int ldoff[2];
  #pragma unroll
  for (int i = 0; i < 2; ++i) {
    int idx = i * 256 + tid;
    int ul = idx >> 3, sl = idx & 7;
    ab[i] = Apk + ((size_t)(U0 + ul) << 12) + (sl << 4);
    wb[i] = Wz  + ((size_t)(V0 + ul) << 12) + (sl << 4);
    ldoff[i] = i * 4096 + (tid >> 6) * 1024;
  }

  f32x16 acc[2][2];
  #pragma unroll
  for (int mi = 0; mi < 2; ++mi)
    #pragma unroll
    for (int ni = 0; ni < 2; ++ni)
      #pragma unroll
      for (int q = 0; q < 16; ++q) acc[mi][ni][q] = 0.f;

  #pragma unroll
  for (int i = 0; i < 2; ++i) {
    async16(ab[i], &Asm[ldoff[i]]);
    async16(wb[i], &Wsm[ldoff[i]]);
  }
  __syncthreads();

  for (int t = 0; t < NKB; ++t) {
    const int c = t & 1;
    if (t + 1 < NKB) {
      #pragma unroll
      for (int i = 0; i < 2; ++i) {
        async16(ab[i] + ((t + 1) << 7), &Asm[(c ^ 1) * 8192 + ldoff[i]]);
        async16(wb[i] + ((t + 1) << 7), &Wsm[(c ^ 1) * 8192 + ldoff[i]]);
      }
    }
    const char* Ab = Asm + c * 8192;
    const char* Wb = Wsm + c * 8192;
    #pragma unroll
    for (int kb = 0; kb < 2; ++kb) {
      const int kq = (kb << 1) | lhalf;
      bf8 a[2], b[2];
      #pragma unroll
      for (int mi = 0; mi < 2; ++mi) {
        int m = wr * 64 + mi * 32 + ln31;
        int u = m >> 1;
        int s = (((m & 1) << 2) | kq) ^ (u & 7);
        a[mi] = *(const bf8*)(Ab + u * 128 + s * 16);
      }
      #pragma unroll
      for (int ni = 0; ni < 2; ++ni) {
        int n = wc * 64 + ni * 32 + ln31;
        int u = n >> 1;
        int s = (((n & 1) << 2) | kq) ^ (u & 7);
        b[ni] = *(const bf8*)(Wb + u * 128 + s * 16);
      }
      #pragma unroll
      for (int mi = 0; mi < 2; ++mi)
        #pragma unroll
        for (int ni = 0; ni < 2; ++ni)
          acc[mi][ni] = __builtin_amdgcn_mfma_f32_32x32x16_bf16(a[mi], b[ni], acc[mi][ni], 0, 0, 0);
    }
    __syncthreads();
  }

  unsigned short* Cb = (z == 0) ? Cb0 : (z == 1) ? Cb1 : Cb2;
  const float sc = (z == 0) ? (1.44269504088896f / 64.0f) : 1.0f;
  #pragma unroll
  for (int ni = 0; ni < 2; ++ni) {
    int col = N0 + wc * 64 + ni * 32 + ln31;
    float bb = Bv[col];
    #pragma unroll
    for (int mi = 0; mi < 2; ++mi)
      #pragma unroll
      for (int r = 0; r < 16; ++r) {
        int row = M0 + wr * 64 + mi * 32 + (r & 3) + ((r >> 2) << 3) + (lhalf << 2);
        Cb[(size_t)row * EMBED + col] = f2bf((acc[mi][ni][r] + bb) * sc);
      }
  }
}

// ---------------------------------------------------------------------------
// Output projection: split-bf16 3-term MFMA GEMM, dbuf 2-phase.
// ---------------------------------------------------------------------------
__global__ __launch_bounds__(256) void gemm_out_split_k(
    const char* __restrict__ Apack, const char* __restrict__ Wpack,
    const float* __restrict__ Bv, float* __restrict__ Cf)
{
  __shared__ __align__(16) char Asm[32768];   // 2 x 16KB
  __shared__ __align__(16) char Wsm[32768];

  const int tid  = threadIdx.x;
  const int lane = tid & 63;
  const int wid  = tid >> 6;
  const int wr   = wid >> 1, wc = wid & 1;
  const int ln31 = lane & 31, lhalf = lane >> 5;

  const int bid = blockIdx.x;                 // 256 blocks
  const int swz = (bid & 7) * 32 + (bid >> 3);
  const int rp  = swz >> 3, cb = swz & 7;

  const int M0 = rp * 128, N0 = cb * 128;
  const int U0 = M0 >> 1, V0 = N0 >> 1;

  const char* ab[4]; const char* wb[4]; int ldoff[4];
  #pragma unroll
  for (int i = 0; i < 4; ++i) {
    int ul = i * 16 + (tid >> 4);
    int so = (tid & 15) << 4;
    ab[i] = Apack + ((size_t)(U0 + ul) << 13) + so;
    wb[i] = Wpack + ((size_t)(V0 + ul) << 13) + so;
    ldoff[i] = i * 4096 + (tid >> 6) * 1024;
  }

  f32x16 acc[2][2];
  #pragma unroll
  for (int mi = 0; mi < 2; ++mi)
    #pragma unroll
    for (int ni = 0; ni < 2; ++ni)
      #pragma unroll
      for (int q = 0; q < 16; ++q) acc[mi][ni][q] = 0.f;

  #pragma unroll
  for (int i = 0; i < 4; ++i) {
    async16(ab[i], &Asm[ldoff[i]]);
    async16(wb[i], &Wsm[ldoff[i]]);
  }
  __syncthreads();

  for (int t = 0; t < NKB; ++t) {
    const int c = t & 1;
    if (t + 1 < NKB) {
      #pragma unroll
      for (int i = 0; i < 4; ++i) {
        async16(ab[i] + ((t + 1) << 8), &Asm[(c ^ 1) * 16384 + ldoff[i]]);
        async16(wb[i] + ((t + 1) << 8), &Wsm[(c ^ 1) * 16384 + ldoff[i]]);
      }
    }
    const char* Ab = Asm + c * 16384;
    const char* Wb = Wsm + c * 16384;
    #pragma unroll
    for (int h = 0; h < 2; ++h) {
      const int kb = h * 2 + lhalf;
      bf8 aH[2], aL[2], bH[2], bL[2];
      #pragma unroll
      for (int mi = 0; mi < 2; ++mi) {
        int m = wr * 64 + mi * 32 + ln31;
        int u = m >> 1;
        int sH = (((m & 1) << 3) | kb) ^ (u & 15);
        aH[mi] = *(const bf8*)(Ab + u * 256 + sH * 16);
        aL[mi] = *(const bf8*)(Ab + u * 256 + (sH ^ 4) * 16);
      }
      #pragma unroll
      for (int ni = 0; ni < 2; ++ni) {
        int n = wc * 64 + ni * 32 + ln31;
        int u = n >> 1;
        int sH = (((n & 1) << 3) | kb) ^ (u & 15);
        bH[ni] = *(const bf8*)(Wb + u * 256 + sH * 16);
        bL[ni] = *(const bf8*)(Wb + u * 256 + (sH ^ 4) * 16);
      }
      #pragma unroll
      for (int mi = 0; mi < 2; ++mi)
        #pragma unroll
        for (int ni = 0; ni < 2; ++ni) {
          acc[mi][ni] = __builtin_amdgcn_mfma_f32_32x32x16_bf16(aH[mi], bH[ni], acc[mi][ni], 0, 0, 0);
          acc[mi][ni] = __builtin_amdgcn_mfma_f32_32x32x16_bf16(aH[mi], bL[ni], acc[mi][ni], 0, 0, 0);
          acc[mi][ni] = __builtin_amdgcn_mfma_f32_32x32x16_bf16(aL[mi], bH[ni], acc[mi][ni], 0, 0, 0);
        }
    }
    __syncthreads();
  }

  #pragma unroll
  for (int ni = 0; ni < 2; ++ni) {
    int col = N0 + wc * 64 + ni * 32 + ln31;
    float bb = Bv[col];
    #pragma unroll
    for (int mi = 0; mi < 2; ++mi)
      #pragma unroll
      for (int r = 0; r < 16; ++r) {
        int row = M0 + wr * 64 + mi * 32 + (r & 3) + ((r >> 2) << 3) + (lhalf << 2);
        Cf[(size_t)row * EMBED + col] = acc[mi][ni][r] + bb;
      }
  }
}

// ---------------------------------------------------------------------------
// MFMA flash attention, log2-domain softmax, defer-max, cvt_pk + permlane.
// ---------------------------------------------------------------------------
__global__ __launch_bounds__(256) void attn_mfma_k(
    const unsigned short* __restrict__ Qb, const unsigned short* __restrict__ Kb,
    const unsigned short* __restrict__ Vb, char* __restrict__ A2)
{
  __shared__ __align__(16) char lds[32768];   // buf c: K @ c*16K, V^T @ c*16K+8K

  const int bid = blockIdx.x;
  const int swz = (bid & 7) * 64 + (bid >> 3);
  const int qt = swz & 15, h = (swz >> 4) & 15, b = swz >> 8;

  const int tid  = threadIdx.x;
  const int lane = tid & 63;
  const int w    = tid >> 6;
  const int ln31 = lane & 31, lh = lane >> 5;
  const int l7   = ln31 & 7;

  const int q0 = qt * 128;

  bf8 qf[4];
  {
    const size_t qoff = (size_t)(b * SEQ + q0 + w * 32 + ln31) * EMBED + h * HDIM;
    #pragma unroll
    for (int kd = 0; kd < 4; ++kd)
      qf[kd] = *(const bf8*)(Qb + qoff + (2 * kd + lh) * 8);
  }

  const unsigned short* ksrc[2]; int kldoff[2];
  #pragma unroll
  for (int i = 0; i < 2; ++i) {
    int idx = i * 256 + tid;
    int r = idx >> 3, s7 = idx & 7;
    int un = s7 ^ (r & 7);
    ksrc[i] = Kb + (size_t)(b * SEQ + r) * EMBED + h * HDIM + un * 8;
    kldoff[i] = i * 4096 + (tid >> 6) * 1024;
  }
  const int kp = tid & 31, d8 = (tid >> 5) << 3;
  const unsigned short* vsrc = Vb + (size_t)(b * SEQ + 2 * kp) * EMBED + h * HDIM + d8;

  us8 v0, v1;
  #pragma unroll
  for (int i = 0; i < 2; ++i) async16(ksrc[i], lds + kldoff[i]);
  v0 = *(const us8*)(vsrc);
  v1 = *(const us8*)(vsrc + EMBED);
  {
    union { us8 v; unsigned u[4]; } U0, U1; U0.v = v0; U1.v = v1;
    #pragma unroll
    for (int q2 = 0; q2 < 4; ++q2) {
      unsigned lo = __builtin_amdgcn_perm(U1.u[q2], U0.u[q2], 0x05040100u);
      unsigned hi = __builtin_amdgcn_perm(U1.u[q2], U0.u[q2], 0x07060302u);
      int d0 = d8 + 2 * q2, d1 = d0 + 1;
      *(unsigned*)(lds + 8192 + d0 * 128 + (((kp >> 2) ^ (d0 & 7)) << 4) + ((kp & 3) << 2)) = lo;
      *(unsigned*)(lds + 8192 + d1 * 128 + (((kp >> 2) ^ (d1 & 7)) << 4) + ((kp & 3) << 2)) = hi;
    }
  }
  __syncthreads();

  f32x16 oacc[2];
  #pragma unroll
  for (int df = 0; df < 2; ++df)
    #pragma unroll
    for (int r = 0; r < 16; ++r) oacc[df][r] = 0.f;
  float m_run = -1e30f, l_run = 0.f;

  for (int t = 0; t < NT; ++t) {
    const int c = t & 1;
    const int tn = (t + 1 < NT) ? t + 1 : t;
    #pragma unroll
    for (int i = 0; i < 2; ++i)
      async16(ksrc[i] + (size_t)(tn * 64) * EMBED, lds + (c ^ 1) * 16384 + kldoff[i]);
    v0 = *(const us8*)(vsrc + (size_t)(tn * 64) * EMBED);
    v1 = *(const us8*)(vsrc + (size_t)(tn * 64) * EMBED + EMBED);

    // S^T = K * Q^T (log2 domain) from buf c
    f32x16 sacc[2];
    #pragma unroll
    for (int kf = 0; kf < 2; ++kf)
      #pragma unroll
      for (int r = 0; r < 16; ++r) sacc[kf][r] = 0.f;
    __builtin_amdgcn_s_setprio(1);
    #pragma unroll
    for (int kf = 0; kf < 2; ++kf)
      #pragma unroll
      for (int kd = 0; kd < 4; ++kd) {
        bf8 ka = *(const bf8*)(lds + c * 16384 + (32 * kf + ln31) * 128 + (((2 * kd + lh) ^ l7) << 4));
        sacc[kf] = __builtin_amdgcn_mfma_f32_32x32x16_bf16(ka, qf[kd], sacc[kf], 0, 0, 0);
      }
    __builtin_amdgcn_s_setprio(0);

    // online softmax, log2 domain, defer-max (T13, THR=8)
    float mx = sacc[0][0];
    #pragma unroll
    for (int kf = 0; kf < 2; ++kf)
      #pragma unroll
      for (int r = 0; r < 16; ++r) mx = fmaxf(mx, sacc[kf][r]);
    {
      i32x2 ms = swap32(__float_as_int(mx), __float_as_int(mx));
      mx = fmaxf(__int_as_float(ms[0]), __int_as_float(ms[1]));
    }
    if (__any(mx - m_run > 8.f)) {
      float mnew = fmaxf(m_run, mx);
      float corr = __builtin_amdgcn_exp2f(m_run - mnew);
      l_run *= corr;
      #pragma unroll
      for (int df = 0; df < 2; ++df)
        #pragma unroll
        for (int r = 0; r < 16; ++r) oacc[df][r] *= corr;
      m_run = mnew;
    }
    float psum = 0.f;
    #pragma unroll
    for (int kf = 0; kf < 2; ++kf)
      #pragma unroll
      for (int r = 0; r < 16; ++r) {
        float p = __builtin_amdgcn_exp2f(sacc[kf][r] - m_run);
        sacc[kf][r] = p; psum += p;
      }
    {
      i32x2 ps = swap32(__float_as_int(psum), __float_as_int(psum));
      psum = __int_as_float(ps[0]) + __int_as_float(ps[1]);
    }
    l_run += psum;

    // write next-tile V^T into buf^1
    {
      union { us8 v; unsigned u[4]; } U0, U1; U0.v = v0; U1.v = v1;
      #pragma unroll
      for (int q2 = 0; q2 < 4; ++q2) {
        unsigned lo = __builtin_amdgcn_perm(U1.u[q2], U0.u[q2], 0x05040100u);
        unsigned hi = __builtin_amdgcn_perm(U1.u[q2], U0.u[q2], 0x07060302u);
        int d0 = d8 + 2 * q2, d1 = d0 + 1;
        *(unsigned*)(lds + (c ^ 1) * 16384 + 8192 + d0 * 128 + (((kp >> 2) ^ (d0 & 7)) << 4) + ((kp & 3) << 2)) = lo;
        *(unsigned*)(lds + (c ^ 1) * 16384 + 8192 + d1 * 128 + (((kp >> 2) ^ (d1 & 7)) << 4) + ((kp & 3) << 2)) = hi;
      }
    }

    // pack P to bf16 pairs (packed cvt)
    unsigned pk[2][8];
    #pragma unroll
    for (int kf = 0; kf < 2; ++kf)
      #pragma unroll
      for (int g = 0; g < 4; ++g)
        #pragma unroll
        for (int j = 0; j < 2; ++j) {
          union { __hip_bfloat162 b; unsigned u; } cv;
          cv.b = __float22bfloat162_rn(
              float2{sacc[kf][4 * g + 2 * j], sacc[kf][4 * g + 2 * j + 1]});
          pk[kf][2 * g + j] = cv.u;
        }

    // O^T += V^T * P^T from buf c
    __builtin_amdgcn_s_setprio(1);
    #pragma unroll
    for (int kb = 0; kb < 4; ++kb) {
      const int kf = kb >> 1, b4 = (kb & 1) * 4;
      i32x2 r02 = swap32((int)pk[kf][b4 + 0], (int)pk[kf][b4 + 2]);
      i32x2 r13 = swap32((int)pk[kf][b4 + 1], (int)pk[kf][b4 + 3]);
      union { unsigned u[4]; bf8 v; } pf;
      pf.u[0] = (unsigned)r02[0]; pf.u[1] = (unsigned)r13[0];
      pf.u[2] = (unsigned)r02[1]; pf.u[3] = (unsigned)r13[1];
      #pragma unroll
      for (int df = 0; df < 2; ++df) {
        bf8 va = *(const bf8*)(lds + c * 16384 + 8192 + (32 * df + ln31) * 128 + (((2 * kb + lh) ^ l7) << 4));
        oacc[df] = __builtin_amdgcn_mfma_f32_32x32x16_bf16(va, pf.v, oacc[df], 0, 0, 0);
      }
    }
    __builtin_amdgcn_s_setprio(0);
    __syncthreads();
  }

  // epilogue: normalize, permlane exchange, write packed split-bf16
  const float inv = 1.0f / l_run;
  float fl[8][4], fh[8][4];
  #pragma unroll
  for (int df = 0; df < 2; ++df)
    #pragma unroll
    for (int r = 0; r < 16; ++r) {
      float o = oacc[df][r] * inv;
      i32x2 rr = swap32(__float_as_int(o), __float_as_int(o));
      fl[df * 4 + (r >> 2)][r & 3] = __int_as_float(rr[0]);
      fh[df * 4 + (r >> 2)][r & 3] = __int_as_float(rr[1]);
    }

  const int row = b * SEQ + q0 + w * 32 + ln31;
  const int u = row >> 1, par = row & 1;
  #pragma unroll
  for (int g = 0; g < 8; ++g) {
    us8 hi, lo;
    #pragma unroll
    for (int e = 0; e < 8; ++e) {
      float f = (e < 4) ? fl[g][e] : fh[g][e - 4];
      unsigned short h8 = f2bf(f);
      hi[e] = h8;
      lo[e] = f2bf(f - bf2f(h8));
    }
    int t_blk = 2 * h + (g >> 2), kb8 = g & 3;
    size_t ub = ((size_t)(u * NKB + t_blk)) << 8;
    int sH = ((par << 3) | kb8) ^ (u & 15);
    *(us8*)(A2 + ub + (sH << 4)) = hi;
    *(us8*)(A2 + ub + ((sH ^ 4) << 4)) = lo;
  }
}

// ---------------------------------------------------------------------------
extern "C" void kernel_launch(void* const* d_in, const int* in_sizes, int n_in,
                              void* d_out, int out_size, void* d_ws, size_t ws_size,
                              hipStream_t stream)
{
  const float* x  = (const float*)d_in[0];
  const float* Wq = (const float*)d_in[1];
  const float* bq = (const float*)d_in[2];
  const float* Wk = (const float*)d_in[3];
  const float* bk = (const float*)d_in[4];
  const float* Wv = (const float*)d_in[5];
  const float* bv = (const float*)d_in[6];
  const float* Wo = (const float*)d_in[7];
  const float* bo = (const float*)d_in[8];
  float* out = (float*)d_out;

  char* wsb = (char*)d_ws;
  char*           Xp  = wsb;                                         // 8MB
  char*           Wp3 = wsb + ((size_t)8  << 20);                    // 6MB
  char*           Wos = wsb + ((size_t)14 << 20);                    // 4MB
  unsigned short* Qbf = (unsigned short*)(wsb + ((size_t)18 << 20)); // 8MB
  unsigned short* Kbf = (unsigned short*)(wsb + ((size_t)26 << 20)); // 8MB
  unsigned short* Vbf = (unsigned short*)(wsb + ((size_t)34 << 20)); // 8MB
  char*           A2  = wsb + ((size_t)42 << 20);                    // 16MB

  pack_all_k<<<dim3(4608), dim3(256), 0, stream>>>(
      x, Wq, Wk, Wv, Wo, Xp, Wp3, Wos);

  gemm_qkv_bf16_k<<<dim3(768), dim3(256), 0, stream>>>(
      Xp, Wp3, bq, bk, bv, Qbf, Kbf, Vbf);

  attn_mfma_k<<<dim3(512), dim3(256), 0, stream>>>(Qbf, Kbf, Vbf, A2);

  gemm_out_split_k<<<dim3(256), dim3(256), 0, stream>>>(A2, Wos, bo, out);
}